// Round 1
// baseline (194.564 us; speedup 1.0000x reference)
//
#include <hip/hip_runtime.h>
#include <stdint.h>

// GeometricBilinear (PGA 3,0,1) — MFMA formulation.
// Per block: 16 positions, 256 threads (4 waves).
// stage1: 4 equi-linears as per-component GEMMs (M=64 stacked L/R/JL/JR, K=32, N=16 pos)
// stage2: channel-local gp/join bilinear on VALU
// stage3: output equi-linear (M=32, K=32 hidden ch) + scalar head (M=64) on MFMA.
//
// R-this-session: LDS regions xs / ylds / hl fully aliased into ONE 37376-B
// buffer (was 57600 B, 2 blocks/CU -> now 4 blocks/CU). Lifetimes are made
// sequential with 2 extra barriers:
//   stage0 writes xs -> B1 -> stage1 reads bx -> B2 -> stage1 writes ylds
//   -> B3 -> stage2 reads L/R rows [0,32) -> B4 -> stage2 writes hl [0,16640)
//   (JL/JR rows [32,64) live at bytes [18688,37376) — disjoint from hl)
//   -> B5 -> stage3 reads hl.
// ylds layout: u32 idx = o*146 + pos*9 + jp (o-stride 584 B ≡ 18 mod 32 u32:
// 2-way-free writes; b32 reads, conflicts halved vs old b64 even-bank reads).

#define NPOS_TOTAL 32768

typedef __attribute__((ext_vector_type(8))) short short8;
typedef __attribute__((ext_vector_type(4))) float f32x4;
#define MFMA16(a,b,c) __builtin_amdgcn_mfma_f32_16x16x32_bf16((a),(b),(c),0,0,0)

// ---------------- constexpr PGA(3,0,1) blade tables (verified R1) ----------------
constexpr int BLADE_MASK[16] = {0,1,2,4,8,3,5,9,6,10,12,7,11,13,14,15};
constexpr int MASK2IDX[16]   = {0,1,2,5,3,6,8,11,4,7,9,12,10,13,14,15};

struct MulRes { int sign; int mask; };

constexpr MulRes mul_blades(int ma, int mb) {
  int lst[8] = {0,0,0,0,0,0,0,0};
  int n = 0;
  for (int g = 0; g < 4; ++g) if ((ma >> g) & 1) lst[n++] = g;
  for (int g = 0; g < 4; ++g) if ((mb >> g) & 1) lst[n++] = g;
  int sign = 1;
  bool changed = true;
  while (changed) {
    changed = false;
    int k = 0;
    while (k + 1 < n) {
      if (lst[k] > lst[k+1]) {
        int t = lst[k]; lst[k] = lst[k+1]; lst[k+1] = t;
        sign = -sign; changed = true;
      } else if (lst[k] == lst[k+1]) {
        if (lst[k] == 0) sign = 0;            // METRIC = [0,1,1,1]
        for (int m = k; m + 2 < n; ++m) lst[m] = lst[m+2];
        n -= 2; changed = true;
      } else {
        ++k;
      }
    }
  }
  int mask = 0;
  for (int m = 0; m < n; ++m) mask |= (1 << lst[m]);
  if (sign == 0) mask = 0;
  return MulRes{sign, mask};
}

struct Tables {
  float gp_sgn[16][16]; int gp_idx[16][16];
  float jn_sgn[16][16]; int jn_idx[16][16];
  constexpr Tables() : gp_sgn{}, gp_idx{}, jn_sgn{}, jn_idx{} {
    for (int j = 0; j < 16; ++j) {
      for (int k = 0; k < 16; ++k) {
        MulRes r = mul_blades(BLADE_MASK[j], BLADE_MASK[k]);
        gp_sgn[j][k] = (float)r.sign;
        gp_idx[j][k] = MASK2IDX[r.mask & 15];
        jn_sgn[j][k] = 0.0f; jn_idx[j][k] = 0;
        int mb = BLADE_MASK[j], mc = BLADE_MASK[k];
        if ((mb | mc) == 15) {
          int cb = 15 ^ mb, cc = 15 ^ mc;
          MulRes sb = mul_blades(mb, cb);
          MulRes sc = mul_blades(mc, cc);
          MulRes ro = mul_blades(cb, cc);
          int imask = ro.mask;
          int amask = 15 ^ imask;
          MulRes si = mul_blades(imask, amask);
          jn_sgn[j][k] = (float)(si.sign * ro.sign * sb.sign * sc.sign);
          jn_idx[j][k] = MASK2IDX[amask & 15];
        }
      }
    }
  }
};
constexpr Tables TBL{};

// grade of each blade, and the e0-wedge (tgt <- src, w-slot) mapping
constexpr int GRADE[16] = {0,1,1,1,1,2,2,2,2,2,2,3,3,3,3,4};
constexpr int E0_TGT[8]  = {1,5,6,7,11,12,13,15};
constexpr int E0_SRC[8]  = {0,2,3,4,8,9,10,14};
constexpr int E0_SLOT[8] = {5,6,6,6,7,7,7,8};

// ---------------- helpers (manual RNE bf16 pack — R1-verified) ----------------
__device__ __forceinline__ float bflo(unsigned u) { return __uint_as_float(u << 16); }
__device__ __forceinline__ float bfhi(unsigned u) { return __uint_as_float(u & 0xffff0000u); }
__device__ __forceinline__ unsigned pk2(float a, float b) {
  unsigned ua = __float_as_uint(a), ub = __float_as_uint(b);
  unsigned ra = (ua + 0x7fffu + ((ua >> 16) & 1u)) >> 16;   // RNE
  unsigned rb = (ub + 0x7fffu + ((ub >> 16) & 1u)) >> 16;
  return (ra & 0xffffu) | ((rb & 0xffffu) << 16);
}
__device__ __forceinline__ unsigned short bf1(float a) {
  unsigned ua = __float_as_uint(a);
  return (unsigned short)((ua + 0x7fffu + ((ua >> 16) & 1u)) >> 16);
}

// ---------------- prep: pack all A-fragments (bf16) into ws ----------------
// 168 fragment blocks of 64 lanes x uint4 (8 bf16 in K order):
//  [0,104)  stage1: blk = mat*4 + ot   (mats: 16 grade, 8 e0, 2 scalar-half; ot 0..3, o=ot*16+m)
//  [104,156) stage3: blk = 104 + mat*2 + ot  (same mat order; ot 0..1, M=32)
//  [156,168) stage4: 156+ot: wm2s (64x32); 160+ot: ws2s half0; 164+ot: ws2s half1
__global__ void gb_prep(const float* __restrict__ wlmv, const float* __restrict__ wrmv,
                        const float* __restrict__ wjlmv, const float* __restrict__ wjrmv,
                        const float* __restrict__ wls,  const float* __restrict__ wrs,
                        const float* __restrict__ wjls, const float* __restrict__ wjrs,
                        const float* __restrict__ womv, const float* __restrict__ ws2mv,
                        const float* __restrict__ wm2s, const float* __restrict__ ws2s,
                        uint4* __restrict__ wpk) {
  int t = blockIdx.x * 256 + threadIdx.x;
  if (t >= 168 * 64) return;
  int blk = t >> 6, l = t & 63;
  int m = l & 15, q = l >> 4;
  float v[8];
  if (blk < 104) {
    int mat = blk >> 2, ot = blk & 3;
    const float* wmv[4] = {wlmv, wrmv, wjlmv, wjrmv};
    const float* wsc[4] = {wls, wrs, wjls, wjrs};
    for (int jj = 0; jj < 8; ++jj) {
      int k = q * 8 + jj;
      if (mat < 16)      v[jj] = wmv[ot][m * 288 + k * 9 + GRADE[mat]];
      else if (mat < 24) v[jj] = wmv[ot][m * 288 + k * 9 + E0_SLOT[mat - 16]];
      else               v[jj] = wsc[ot][m * 64 + (mat - 24) * 32 + k];
    }
  } else if (blk < 156) {
    int b2 = blk - 104, mat = b2 >> 1, ot = b2 & 1;
    int o = ot * 16 + m;
    for (int jj = 0; jj < 8; ++jj) {
      int k = q * 8 + jj;
      if (mat < 16)      v[jj] = womv[o * 288 + k * 9 + GRADE[mat]];
      else if (mat < 24) v[jj] = womv[o * 288 + k * 9 + E0_SLOT[mat - 16]];
      else               v[jj] = ws2mv[o * 64 + (mat - 24) * 32 + k];
    }
  } else {
    int b4 = blk - 156;
    for (int jj = 0; jj < 8; ++jj) {
      int k = q * 8 + jj;
      if (b4 < 4) { int o = b4 * 16 + m; v[jj] = wm2s[o * 32 + k]; }
      else { int half = (b4 - 4) >> 2, ot = (b4 - 4) & 3; int o = ot * 16 + m;
             v[jj] = ws2s[o * 64 + half * 32 + k]; }
    }
  }
  uint4 u;
  u.x = pk2(v[0], v[1]); u.y = pk2(v[2], v[3]);
  u.z = pk2(v[4], v[5]); u.w = pk2(v[6], v[7]);
  wpk[t] = u;
}

// ---------------- main fused kernel ----------------
// Single aliased LDS buffer, 37376 B:
//  phase xs  [0,16640): halfword idx p*520 + c*32 + i          (stage0 -> stage1)
//  phase yl  [0,37376): u32 idx o*146 + pos*9 + jp             (stage1 -> stage2)
//  phase hl  [0,16640): halfword idx pos*520 + j*32 + ch       (stage2 -> stage3)
__global__ __launch_bounds__(256, 4) void gb_main(
    const float* __restrict__ mv, const float* __restrict__ ref,
    const float* __restrict__ s, const uint4* __restrict__ wpk,
    float* __restrict__ out_mv, float* __restrict__ out_s) {
  __shared__ __align__(16) char smem[37376];
  unsigned short* xs_e = (unsigned short*)smem;
  unsigned*       xs_w = (unsigned*)smem;
  unsigned short* hl_e = (unsigned short*)smem;
  unsigned*       yl_w = (unsigned*)smem;

  const int tid  = threadIdx.x;
  const int wave = tid >> 6, lane = tid & 63;
  const int lm = lane & 15, lq = lane >> 4;
  const int P0 = blockIdx.x * 16;

  // ref scale: load early (used in stage2); hides global latency under stage0/1.
  const float rs = ref[((size_t)(P0 + (tid & 15))) * 16 + 15];

  // ---- stage 0: transpose mv tile into xs (bf16) ----
  const float4* mv4 = (const float4*)mv + (size_t)P0 * 128;
  #pragma unroll
  for (int kk = 0; kk < 4; ++kk) {
    int e = tid + kk * 256;              // 0..1023 tasks
    int p = e >> 6, sub = e & 63, i2 = sub >> 2, jg = sub & 3;
    float4 fa = mv4[p * 128 + i2 * 8 + jg];
    float4 fb = mv4[p * 128 + i2 * 8 + 4 + jg];
    int base = p * 260 + jg * 4 * 16 + i2;     // u32 index: [p][c][i-pair]
    xs_w[base + 0 * 16] = pk2(fa.x, fb.x);
    xs_w[base + 1 * 16] = pk2(fa.y, fb.y);
    xs_w[base + 2 * 16] = pk2(fa.z, fb.z);
    xs_w[base + 3 * 16] = pk2(fa.w, fb.w);
  }

  // ---- s B-fragments (K=64 -> 2 frags), per lane: pos=lm, k=half*32+lq*8+jj ----
  short8 sfrag[2];
  {
    const float4* s4 = (const float4*)s + ((size_t)(P0 + lm)) * 16;
    #pragma unroll
    for (int h = 0; h < 2; ++h) {
      float4 a = s4[h * 8 + lq * 2];
      float4 b = s4[h * 8 + lq * 2 + 1];
      uint4 u;
      u.x = pk2(a.x, a.y); u.y = pk2(a.z, a.w);
      u.z = pk2(b.x, b.y); u.w = pk2(b.z, b.w);
      sfrag[h] = __builtin_bit_cast(short8, u);
    }
  }
  __syncthreads();                                           // B1: xs ready

  // ---- stage 1: 64-row stacked equi-linear via MFMA (this wave: o-tile = wave) ----
  {
    short8 bx[16];
    #pragma unroll
    for (int c = 0; c < 16; ++c)
      bx[c] = *(const short8*)&xs_e[lm * 520 + c * 32 + lq * 8];
    __syncthreads();                                         // B2: xs consumed -> yl may alias
    f32x4 zf = {0.f, 0.f, 0.f, 0.f};
    f32x4 acc[16];
    #pragma unroll
    for (int j = 0; j < 16; ++j) acc[j] = zf;
    #pragma unroll
    for (int j = 0; j < 16; ++j) {
      short8 w = __builtin_bit_cast(short8, wpk[(j * 4 + wave) * 64 + lane]);
      acc[j] = MFMA16(w, bx[j], acc[j]);
    }
    #pragma unroll
    for (int m = 0; m < 8; ++m) {
      short8 w = __builtin_bit_cast(short8, wpk[((16 + m) * 4 + wave) * 64 + lane]);
      acc[E0_TGT[m]] = MFMA16(w, bx[E0_SRC[m]], acc[E0_TGT[m]]);
    }
    #pragma unroll
    for (int h = 0; h < 2; ++h) {
      short8 w = __builtin_bit_cast(short8, wpk[((24 + h) * 4 + wave) * 64 + lane]);
      acc[0] = MFMA16(w, sfrag[h], acc[0]);
    }
    // D-frag: lane holds out[o = wave*16 + lq*4 + r][pos = lm]; pack j-pairs -> yl
    #pragma unroll
    for (int jp = 0; jp < 8; ++jp) {
      #pragma unroll
      for (int r = 0; r < 4; ++r) {
        int o = wave * 16 + lq * 4 + r;
        yl_w[o * 146 + lm * 9 + jp] = pk2(acc[2 * jp][r], acc[2 * jp + 1][r]);
      }
    }
  }
  __syncthreads();                                           // B3: yl ready

  // ---- stage 2: channel-local bilinear (VALU). thread t: pos=t&15, hc=t>>4 ----
  {
    const int pos = tid & 15;
    const int hc  = tid >> 4;
    // read L,R rows (yl rows [0,32) = bytes [0,18688)) BEFORE hl overwrites [0,16640)
    unsigned uL[8], uR[8];
    {
      const unsigned* pL = yl_w + hc * 146 + pos * 9;
      const unsigned* pR = yl_w + (16 + hc) * 146 + pos * 9;
      #pragma unroll
      for (int q = 0; q < 8; ++q) uL[q] = pL[q];
      #pragma unroll
      for (int q = 0; q < 8; ++q) uR[q] = pR[q];
    }
    __syncthreads();                                         // B4: L/R consumed -> hl may alias
    float L[16], R[16], H[16];
    #pragma unroll
    for (int q = 0; q < 8; ++q) {
      L[2*q] = bflo(uL[q]); L[2*q+1] = bfhi(uL[q]);
      R[2*q] = bflo(uR[q]); R[2*q+1] = bfhi(uR[q]);
    }
    // gp pair -> hidden channel hc
    #pragma unroll
    for (int q = 0; q < 16; ++q) H[q] = 0.f;
    #pragma unroll
    for (int j = 0; j < 16; ++j)
      #pragma unroll
      for (int k = 0; k < 16; ++k)
        if (TBL.gp_sgn[j][k] != 0.0f)
          H[TBL.gp_idx[j][k]] += TBL.gp_sgn[j][k] * L[j] * R[k];
    #pragma unroll
    for (int j = 0; j < 16; ++j)
      hl_e[pos * 520 + j * 32 + hc] = bf1(H[j]);
    // join pair -> hidden channel 16+hc (fold ref scale into L)
    // JL/JR = yl rows [32,64) = bytes [18688,37376): disjoint from hl writes.
    {
      const unsigned* pJ = yl_w + (32 + hc) * 146 + pos * 9;
      const unsigned* pK = yl_w + (48 + hc) * 146 + pos * 9;
      #pragma unroll
      for (int q = 0; q < 8; ++q) {
        unsigned a = pJ[q];
        L[2*q] = bflo(a) * rs; L[2*q+1] = bfhi(a) * rs;
      }
      #pragma unroll
      for (int q = 0; q < 8; ++q) {
        unsigned a = pK[q];
        R[2*q] = bflo(a); R[2*q+1] = bfhi(a);
      }
    }
    #pragma unroll
    for (int q = 0; q < 16; ++q) H[q] = 0.f;
    #pragma unroll
    for (int j = 0; j < 16; ++j)
      #pragma unroll
      for (int k = 0; k < 16; ++k)
        if (TBL.jn_sgn[j][k] != 0.0f)
          H[TBL.jn_idx[j][k]] += TBL.jn_sgn[j][k] * L[j] * R[k];
    #pragma unroll
    for (int j = 0; j < 16; ++j)
      hl_e[pos * 520 + j * 32 + 16 + hc] = bf1(H[j]);
  }
  __syncthreads();                                           // B5: hl ready

  // ---- stage 3 (waves 0,1): output equi-linear. stage 4 (waves 2,3): scalar head ----
  if (wave < 2) {
    short8 bh[16];
    #pragma unroll
    for (int j = 0; j < 16; ++j)
      bh[j] = *(const short8*)&hl_e[lm * 520 + j * 32 + lq * 8];
    f32x4 zf = {0.f, 0.f, 0.f, 0.f};
    f32x4 a3[16];
    #pragma unroll
    for (int j = 0; j < 16; ++j) a3[j] = zf;
    #pragma unroll
    for (int j = 0; j < 16; ++j) {
      short8 w = __builtin_bit_cast(short8, wpk[(104 + j * 2 + wave) * 64 + lane]);
      a3[j] = MFMA16(w, bh[j], a3[j]);
    }
    #pragma unroll
    for (int m = 0; m < 8; ++m) {
      short8 w = __builtin_bit_cast(short8, wpk[(104 + (16 + m) * 2 + wave) * 64 + lane]);
      a3[E0_TGT[m]] = MFMA16(w, bh[E0_SRC[m]], a3[E0_TGT[m]]);
    }
    #pragma unroll
    for (int h = 0; h < 2; ++h) {
      short8 w = __builtin_bit_cast(short8, wpk[(104 + (24 + h) * 2 + wave) * 64 + lane]);
      a3[0] = MFMA16(w, sfrag[h], a3[0]);
    }
    // store: out_mv[pos][o][j], o = wave*16 + lq*4 + r, pos = lm; vectorize over j
    float* ob = out_mv + ((size_t)(P0 + lm)) * 512 + (size_t)(wave * 16 + lq * 4) * 16;
    #pragma unroll
    for (int r = 0; r < 4; ++r) {
      #pragma unroll
      for (int g = 0; g < 4; ++g) {
        *(float4*)(ob + r * 16 + g * 4) =
            make_float4(a3[4*g][r], a3[4*g+1][r], a3[4*g+2][r], a3[4*g+3][r]);
      }
    }
  } else {
    short8 bh0 = *(const short8*)&hl_e[lm * 520 + lq * 8];
    int w2 = wave - 2;
    f32x4 zf = {0.f, 0.f, 0.f, 0.f};
    #pragma unroll
    for (int t2 = 0; t2 < 2; ++t2) {
      int otg = w2 * 2 + t2;
      f32x4 aS = zf;
      aS = MFMA16(__builtin_bit_cast(short8, wpk[(156 + otg) * 64 + lane]), bh0, aS);
      aS = MFMA16(__builtin_bit_cast(short8, wpk[(160 + otg) * 64 + lane]), sfrag[0], aS);
      aS = MFMA16(__builtin_bit_cast(short8, wpk[(164 + otg) * 64 + lane]), sfrag[1], aS);
      float* osb = out_s + ((size_t)(P0 + lm)) * 64 + otg * 16 + lq * 4;
      *(float4*)osb = make_float4(aS[0], aS[1], aS[2], aS[3]);
    }
  }
}

extern "C" void kernel_launch(void* const* d_in, const int* in_sizes, int n_in,
                              void* d_out, int out_size, void* d_ws, size_t ws_size,
                              hipStream_t stream) {
  (void)in_sizes; (void)n_in; (void)out_size; (void)ws_size;
  const float* mv    = (const float*)d_in[0];
  const float* ref   = (const float*)d_in[1];
  const float* s     = (const float*)d_in[2];
  // d_in[3..5] = basis/gp/jn tables: baked at compile time.
  const float* wlmv  = (const float*)d_in[6];
  const float* wls   = (const float*)d_in[7];
  const float* wrmv  = (const float*)d_in[8];
  const float* wrs   = (const float*)d_in[9];
  const float* wjlmv = (const float*)d_in[10];
  const float* wjls  = (const float*)d_in[11];
  const float* wjrmv = (const float*)d_in[12];
  const float* wjrs  = (const float*)d_in[13];
  const float* womv  = (const float*)d_in[14];
  const float* ws2mv = (const float*)d_in[15];
  const float* wm2s  = (const float*)d_in[16];
  const float* ws2s  = (const float*)d_in[17];

  float* out_mv = (float*)d_out;
  float* out_s  = out_mv + (size_t)NPOS_TOTAL * 32 * 16;
  uint4* wpk = (uint4*)d_ws;

  gb_prep<<<42, 256, 0, stream>>>(wlmv, wrmv, wjlmv, wjrmv, wls, wrs, wjls, wjrs,
                                  womv, ws2mv, wm2s, ws2s, wpk);
  gb_main<<<NPOS_TOTAL / 16, 256, 0, stream>>>(mv, ref, s, wpk, out_mv, out_s);
}

// Round 2
// 186.066 us; speedup vs baseline: 1.0457x; 1.0457x over previous
//
#include <hip/hip_runtime.h>
#include <stdint.h>

// GeometricBilinear (PGA 3,0,1) — MFMA formulation.
// Per block: 16 positions, 256 threads (4 waves).
// stage1: 4 equi-linears as per-component GEMMs (M=64 stacked L/R/JL/JR, K=32, N=16 pos)
// stage2: channel-local gp/join bilinear on VALU
// stage3: output equi-linear (M=32, K=32 hidden ch) + scalar head (M=64) on MFMA.
//
// R2: weight-fragment DEDUP + register prefetch.
//  - All blades of one grade share one A-fragment (GRADE[j]): 26 frags/wave -> 11 distinct
//    (5 grade + 4 e0-slot + 2 scalar). Same for stage3. wpk shrinks 168 -> 78 frags.
//  - 5 stage1 grade frags prefetched BEFORE B1: the barrier's vmcnt(0) drain absorbs
//    their latency. Stage3/4 frags (11 resp. 6) prefetched before B5, hidden under
//    stage2 VALU.
//  - __launch_bounds__(256,2): ~220 VGPR peak, no spills (R1's (256,4) squeeze to 64
//    VGPR caused scratch traffic + serialized weight loads).
//  - 3 barriers: xs/hl alias [0,16640), yl separate at +16640 (37376 B), total 54016 B.

#define NPOS_TOTAL 32768

typedef __attribute__((ext_vector_type(8))) short short8;
typedef __attribute__((ext_vector_type(4))) float f32x4;
#define MFMA16(a,b,c) __builtin_amdgcn_mfma_f32_16x16x32_bf16((a),(b),(c),0,0,0)

// ---------------- constexpr PGA(3,0,1) blade tables (verified R1) ----------------
constexpr int BLADE_MASK[16] = {0,1,2,4,8,3,5,9,6,10,12,7,11,13,14,15};
constexpr int MASK2IDX[16]   = {0,1,2,5,3,6,8,11,4,7,9,12,10,13,14,15};

struct MulRes { int sign; int mask; };

constexpr MulRes mul_blades(int ma, int mb) {
  int lst[8] = {0,0,0,0,0,0,0,0};
  int n = 0;
  for (int g = 0; g < 4; ++g) if ((ma >> g) & 1) lst[n++] = g;
  for (int g = 0; g < 4; ++g) if ((mb >> g) & 1) lst[n++] = g;
  int sign = 1;
  bool changed = true;
  while (changed) {
    changed = false;
    int k = 0;
    while (k + 1 < n) {
      if (lst[k] > lst[k+1]) {
        int t = lst[k]; lst[k] = lst[k+1]; lst[k+1] = t;
        sign = -sign; changed = true;
      } else if (lst[k] == lst[k+1]) {
        if (lst[k] == 0) sign = 0;            // METRIC = [0,1,1,1]
        for (int m = k; m + 2 < n; ++m) lst[m] = lst[m+2];
        n -= 2; changed = true;
      } else {
        ++k;
      }
    }
  }
  int mask = 0;
  for (int m = 0; m < n; ++m) mask |= (1 << lst[m]);
  if (sign == 0) mask = 0;
  return MulRes{sign, mask};
}

struct Tables {
  float gp_sgn[16][16]; int gp_idx[16][16];
  float jn_sgn[16][16]; int jn_idx[16][16];
  constexpr Tables() : gp_sgn{}, gp_idx{}, jn_sgn{}, jn_idx{} {
    for (int j = 0; j < 16; ++j) {
      for (int k = 0; k < 16; ++k) {
        MulRes r = mul_blades(BLADE_MASK[j], BLADE_MASK[k]);
        gp_sgn[j][k] = (float)r.sign;
        gp_idx[j][k] = MASK2IDX[r.mask & 15];
        jn_sgn[j][k] = 0.0f; jn_idx[j][k] = 0;
        int mb = BLADE_MASK[j], mc = BLADE_MASK[k];
        if ((mb | mc) == 15) {
          int cb = 15 ^ mb, cc = 15 ^ mc;
          MulRes sb = mul_blades(mb, cb);
          MulRes sc = mul_blades(mc, cc);
          MulRes ro = mul_blades(cb, cc);
          int imask = ro.mask;
          int amask = 15 ^ imask;
          MulRes si = mul_blades(imask, amask);
          jn_sgn[j][k] = (float)(si.sign * ro.sign * sb.sign * sc.sign);
          jn_idx[j][k] = MASK2IDX[amask & 15];
        }
      }
    }
  }
};
constexpr Tables TBL{};

// grade of each blade, and the e0-wedge (tgt <- src, w-slot) mapping
constexpr int GRADE[16] = {0,1,1,1,1,2,2,2,2,2,2,3,3,3,3,4};
constexpr int E0_TGT[8]  = {1,5,6,7,11,12,13,15};
constexpr int E0_SRC[8]  = {0,2,3,4,8,9,10,14};
constexpr int E0_SLOT[8] = {5,6,6,6,7,7,7,8};

// ---------------- helpers (manual RNE bf16 pack — R1-verified) ----------------
__device__ __forceinline__ float bflo(unsigned u) { return __uint_as_float(u << 16); }
__device__ __forceinline__ float bfhi(unsigned u) { return __uint_as_float(u & 0xffff0000u); }
__device__ __forceinline__ unsigned pk2(float a, float b) {
  unsigned ua = __float_as_uint(a), ub = __float_as_uint(b);
  unsigned ra = (ua + 0x7fffu + ((ua >> 16) & 1u)) >> 16;   // RNE
  unsigned rb = (ub + 0x7fffu + ((ub >> 16) & 1u)) >> 16;
  return (ra & 0xffffu) | ((rb & 0xffffu) << 16);
}
__device__ __forceinline__ unsigned short bf1(float a) {
  unsigned ua = __float_as_uint(a);
  return (unsigned short)((ua + 0x7fffu + ((ua >> 16) & 1u)) >> 16);
}

// ---------------- prep: pack DISTINCT A-fragments (bf16) into ws ----------------
// 78 fragment blocks of 64 lanes x uint4 (8 bf16 in K order):
//  [0,36)   stage1 grade/e0 slots: blk = slot*4 + ot   (slot 0..8; ot 0..3 = L/R/JL/JR)
//  [36,44)  stage1 scalar: blk = 36 + h*4 + ot         (h = K-half of IN_S=64)
//  [44,62)  stage3 slots:  blk = 44 + slot*2 + ot      (ot 0..1, o = ot*16+m)
//  [62,66)  stage3 scalar: blk = 62 + h*2 + ot
//  [66,70)  stage4 wm2s:   blk = 66 + ot               (ot 0..3, o = ot*16+m, K=32)
//  [70,78)  stage4 ws2s:   blk = 70 + half*4 + ot
__global__ void gb_prep(const float* __restrict__ wlmv, const float* __restrict__ wrmv,
                        const float* __restrict__ wjlmv, const float* __restrict__ wjrmv,
                        const float* __restrict__ wls,  const float* __restrict__ wrs,
                        const float* __restrict__ wjls, const float* __restrict__ wjrs,
                        const float* __restrict__ womv, const float* __restrict__ ws2mv,
                        const float* __restrict__ wm2s, const float* __restrict__ ws2s,
                        uint4* __restrict__ wpk) {
  int t = blockIdx.x * 256 + threadIdx.x;
  if (t >= 78 * 64) return;
  int blk = t >> 6, l = t & 63;
  int m = l & 15, q = l >> 4;
  float v[8];
  if (blk < 36) {                      // stage1 mv slots
    int slot = blk >> 2, ot = blk & 3;
    const float* wmv[4] = {wlmv, wrmv, wjlmv, wjrmv};
    for (int jj = 0; jj < 8; ++jj) {
      int k = q * 8 + jj;
      v[jj] = wmv[ot][m * 288 + k * 9 + slot];
    }
  } else if (blk < 44) {               // stage1 scalar
    int b = blk - 36, h = b >> 2, ot = b & 3;
    const float* wsc[4] = {wls, wrs, wjls, wjrs};
    for (int jj = 0; jj < 8; ++jj) {
      int k = q * 8 + jj;
      v[jj] = wsc[ot][m * 64 + h * 32 + k];
    }
  } else if (blk < 62) {               // stage3 mv slots
    int b = blk - 44, slot = b >> 1, ot = b & 1;
    int o = ot * 16 + m;
    for (int jj = 0; jj < 8; ++jj) {
      int k = q * 8 + jj;
      v[jj] = womv[o * 288 + k * 9 + slot];
    }
  } else if (blk < 66) {               // stage3 scalar (ws2mv)
    int b = blk - 62, h = b >> 1, ot = b & 1;
    int o = ot * 16 + m;
    for (int jj = 0; jj < 8; ++jj) {
      int k = q * 8 + jj;
      v[jj] = ws2mv[o * 64 + h * 32 + k];
    }
  } else if (blk < 70) {               // stage4 wm2s (64x32)
    int ot = blk - 66, o = ot * 16 + m;
    for (int jj = 0; jj < 8; ++jj) {
      int k = q * 8 + jj;
      v[jj] = wm2s[o * 32 + k];
    }
  } else {                             // stage4 ws2s (64x64, two K-halves)
    int b = blk - 70, half = b >> 2, ot = b & 3;
    int o = ot * 16 + m;
    for (int jj = 0; jj < 8; ++jj) {
      int k = q * 8 + jj;
      v[jj] = ws2s[o * 64 + half * 32 + k];
    }
  }
  uint4 u;
  u.x = pk2(v[0], v[1]); u.y = pk2(v[2], v[3]);
  u.z = pk2(v[4], v[5]); u.w = pk2(v[6], v[7]);
  wpk[t] = u;
}

// ---------------- main fused kernel ----------------
// LDS 54016 B, 3 barriers:
//  xs  [0,16640)  halfword idx p*520 + c*32 + i      (stage0 -> stage1)
//  yl  [16640,54016) u32 idx o*146 + pos*9 + jp      (stage1 -> stage2)
//  hl  [0,16640)  halfword idx pos*520 + j*32 + ch   (stage2 -> stage3; aliases xs —
//                  safe: all xs reads happen before B3, all hl writes after B3)
__global__ __launch_bounds__(256, 2) void gb_main(
    const float* __restrict__ mv, const float* __restrict__ ref,
    const float* __restrict__ s, const uint4* __restrict__ wpk,
    float* __restrict__ out_mv, float* __restrict__ out_s) {
  __shared__ __align__(16) char smem[54016];
  unsigned short* xs_e = (unsigned short*)smem;
  unsigned*       xs_w = (unsigned*)smem;
  unsigned short* hl_e = (unsigned short*)smem;
  unsigned*       yl_w = (unsigned*)(smem + 16640);

  const int tid  = threadIdx.x;
  const int wave = tid >> 6, lane = tid & 63;
  const int lm = lane & 15, lq = lane >> 4;
  const int P0 = blockIdx.x * 16;

  // ---- stage1 weight prefetch: 5 grade frags for this wave's o-tile.
  // Issued before B1 so the barrier's vmcnt(0) drain completes them for free.
  short8 wg[5];
  #pragma unroll
  for (int g = 0; g < 5; ++g)
    wg[g] = __builtin_bit_cast(short8, wpk[(g * 4 + wave) * 64 + lane]);

  // ref scale: load early (used in stage2).
  const float rs = ref[((size_t)(P0 + (tid & 15))) * 16 + 15];

  // ---- stage 0: transpose mv tile into xs (bf16) ----
  const float4* mv4 = (const float4*)mv + (size_t)P0 * 128;
  #pragma unroll
  for (int kk = 0; kk < 4; ++kk) {
    int e = tid + kk * 256;              // 0..1023 tasks
    int p = e >> 6, sub = e & 63, i2 = sub >> 2, jg = sub & 3;
    float4 fa = mv4[p * 128 + i2 * 8 + jg];
    float4 fb = mv4[p * 128 + i2 * 8 + 4 + jg];
    int base = p * 260 + jg * 4 * 16 + i2;     // u32 index: [p][c][i-pair]
    xs_w[base + 0 * 16] = pk2(fa.x, fb.x);
    xs_w[base + 1 * 16] = pk2(fa.y, fb.y);
    xs_w[base + 2 * 16] = pk2(fa.z, fb.z);
    xs_w[base + 3 * 16] = pk2(fa.w, fb.w);
  }

  // ---- s B-fragments (K=64 -> 2 frags), per lane: pos=lm, k=half*32+lq*8+jj ----
  short8 sfrag[2];
  {
    const float4* s4 = (const float4*)s + ((size_t)(P0 + lm)) * 16;
    #pragma unroll
    for (int h = 0; h < 2; ++h) {
      float4 a = s4[h * 8 + lq * 2];
      float4 b = s4[h * 8 + lq * 2 + 1];
      uint4 u;
      u.x = pk2(a.x, a.y); u.y = pk2(a.z, a.w);
      u.z = pk2(b.x, b.y); u.w = pk2(b.z, b.w);
      sfrag[h] = __builtin_bit_cast(short8, u);
    }
  }
  __syncthreads();                                           // B1: xs ready, wg in regs

  // ---- stage 1: 64-row stacked equi-linear via MFMA (this wave: o-tile = wave) ----
  {
    short8 bx[16];
    #pragma unroll
    for (int c = 0; c < 16; ++c)
      bx[c] = *(const short8*)&xs_e[lm * 520 + c * 32 + lq * 8];
    // e0 + scalar frags: issued here, latency hidden under the 16 grade MFMAs.
    short8 we[4];
    #pragma unroll
    for (int sidx = 0; sidx < 4; ++sidx)
      we[sidx] = __builtin_bit_cast(short8, wpk[((5 + sidx) * 4 + wave) * 64 + lane]);
    short8 wsc1[2];
    #pragma unroll
    for (int h = 0; h < 2; ++h)
      wsc1[h] = __builtin_bit_cast(short8, wpk[(36 + h * 4 + wave) * 64 + lane]);

    f32x4 zf = {0.f, 0.f, 0.f, 0.f};
    f32x4 acc[16];
    #pragma unroll
    for (int j = 0; j < 16; ++j) acc[j] = zf;
    #pragma unroll
    for (int j = 0; j < 16; ++j)
      acc[j] = MFMA16(wg[GRADE[j]], bx[j], acc[j]);
    #pragma unroll
    for (int m = 0; m < 8; ++m)
      acc[E0_TGT[m]] = MFMA16(we[E0_SLOT[m] - 5], bx[E0_SRC[m]], acc[E0_TGT[m]]);
    #pragma unroll
    for (int h = 0; h < 2; ++h)
      acc[0] = MFMA16(wsc1[h], sfrag[h], acc[0]);
    // D-frag: lane holds out[o = wave*16 + lq*4 + r][pos = lm]; pack j-pairs -> yl
    #pragma unroll
    for (int jp = 0; jp < 8; ++jp) {
      #pragma unroll
      for (int r = 0; r < 4; ++r) {
        int o = wave * 16 + lq * 4 + r;
        yl_w[o * 146 + lm * 9 + jp] = pk2(acc[2 * jp][r], acc[2 * jp + 1][r]);
      }
    }
  }
  __syncthreads();                                           // B3: yl ready

  // ---- stage 2: channel-local bilinear (VALU). thread t: pos=t&15, hc=t>>4 ----
  {
    const int pos = tid & 15;
    const int hc  = tid >> 4;
    float L[16], R[16], H[16];
    {
      const unsigned* pL = yl_w + hc * 146 + pos * 9;
      const unsigned* pR = yl_w + (16 + hc) * 146 + pos * 9;
      #pragma unroll
      for (int q = 0; q < 8; ++q) {
        unsigned a = pL[q], b = pR[q];
        L[2*q] = bflo(a); L[2*q+1] = bfhi(a);
        R[2*q] = bflo(b); R[2*q+1] = bfhi(b);
      }
    }
    // gp pair -> hidden channel hc
    #pragma unroll
    for (int q = 0; q < 16; ++q) H[q] = 0.f;
    #pragma unroll
    for (int j = 0; j < 16; ++j)
      #pragma unroll
      for (int k = 0; k < 16; ++k)
        if (TBL.gp_sgn[j][k] != 0.0f)
          H[TBL.gp_idx[j][k]] += TBL.gp_sgn[j][k] * L[j] * R[k];
    #pragma unroll
    for (int j = 0; j < 16; ++j)
      hl_e[pos * 520 + j * 32 + hc] = bf1(H[j]);
    // join pair -> hidden channel 16+hc (fold ref scale into L)
    {
      const unsigned* pJ = yl_w + (32 + hc) * 146 + pos * 9;
      const unsigned* pK = yl_w + (48 + hc) * 146 + pos * 9;
      #pragma unroll
      for (int q = 0; q < 8; ++q) {
        unsigned a = pJ[q];
        L[2*q] = bflo(a) * rs; L[2*q+1] = bfhi(a) * rs;
      }
      #pragma unroll
      for (int q = 0; q < 8; ++q) {
        unsigned a = pK[q];
        R[2*q] = bflo(a); R[2*q+1] = bfhi(a);
      }
    }
    #pragma unroll
    for (int q = 0; q < 16; ++q) H[q] = 0.f;
    #pragma unroll
    for (int j = 0; j < 16; ++j)
      #pragma unroll
      for (int k = 0; k < 16; ++k)
        if (TBL.jn_sgn[j][k] != 0.0f)
          H[TBL.jn_idx[j][k]] += TBL.jn_sgn[j][k] * L[j] * R[k];
    #pragma unroll
    for (int j = 0; j < 16; ++j)
      hl_e[pos * 520 + j * 32 + 16 + hc] = bf1(H[j]);
  }

  // ---- stage3/4 weight prefetch: issued before B5 so the drain absorbs latency ----
  short8 w3[11];
  if (wave < 2) {
    #pragma unroll
    for (int g = 0; g < 9; ++g)
      w3[g] = __builtin_bit_cast(short8, wpk[(44 + g * 2 + wave) * 64 + lane]);
    #pragma unroll
    for (int h = 0; h < 2; ++h)
      w3[9 + h] = __builtin_bit_cast(short8, wpk[(62 + h * 2 + wave) * 64 + lane]);
  } else {
    int w2 = wave - 2;
    #pragma unroll
    for (int t2 = 0; t2 < 2; ++t2) {
      int otg = w2 * 2 + t2;
      w3[t2 * 3 + 0] = __builtin_bit_cast(short8, wpk[(66 + otg) * 64 + lane]);
      w3[t2 * 3 + 1] = __builtin_bit_cast(short8, wpk[(70 + otg) * 64 + lane]);
      w3[t2 * 3 + 2] = __builtin_bit_cast(short8, wpk[(74 + otg) * 64 + lane]);
    }
  }
  __syncthreads();                                           // B5: hl ready, w3 in regs

  // ---- stage 3 (waves 0,1): output equi-linear. stage 4 (waves 2,3): scalar head ----
  if (wave < 2) {
    short8 bh[16];
    #pragma unroll
    for (int j = 0; j < 16; ++j)
      bh[j] = *(const short8*)&hl_e[lm * 520 + j * 32 + lq * 8];
    f32x4 zf = {0.f, 0.f, 0.f, 0.f};
    f32x4 a3[16];
    #pragma unroll
    for (int j = 0; j < 16; ++j) a3[j] = zf;
    #pragma unroll
    for (int j = 0; j < 16; ++j)
      a3[j] = MFMA16(w3[GRADE[j]], bh[j], a3[j]);
    #pragma unroll
    for (int m = 0; m < 8; ++m)
      a3[E0_TGT[m]] = MFMA16(w3[E0_SLOT[m]], bh[E0_SRC[m]], a3[E0_TGT[m]]);
    #pragma unroll
    for (int h = 0; h < 2; ++h)
      a3[0] = MFMA16(w3[9 + h], sfrag[h], a3[0]);
    // store: out_mv[pos][o][j], o = wave*16 + lq*4 + r, pos = lm; vectorize over j
    float* ob = out_mv + ((size_t)(P0 + lm)) * 512 + (size_t)(wave * 16 + lq * 4) * 16;
    #pragma unroll
    for (int r = 0; r < 4; ++r) {
      #pragma unroll
      for (int g = 0; g < 4; ++g) {
        *(float4*)(ob + r * 16 + g * 4) =
            make_float4(a3[4*g][r], a3[4*g+1][r], a3[4*g+2][r], a3[4*g+3][r]);
      }
    }
  } else {
    short8 bh0 = *(const short8*)&hl_e[lm * 520 + lq * 8];
    f32x4 zf = {0.f, 0.f, 0.f, 0.f};
    #pragma unroll
    for (int t2 = 0; t2 < 2; ++t2) {
      int otg = (wave - 2) * 2 + t2;
      f32x4 aS = zf;
      aS = MFMA16(w3[t2 * 3 + 0], bh0, aS);
      aS = MFMA16(w3[t2 * 3 + 1], sfrag[0], aS);
      aS = MFMA16(w3[t2 * 3 + 2], sfrag[1], aS);
      float* osb = out_s + ((size_t)(P0 + lm)) * 64 + otg * 16 + lq * 4;
      *(float4*)osb = make_float4(aS[0], aS[1], aS[2], aS[3]);
    }
  }
}

extern "C" void kernel_launch(void* const* d_in, const int* in_sizes, int n_in,
                              void* d_out, int out_size, void* d_ws, size_t ws_size,
                              hipStream_t stream) {
  (void)in_sizes; (void)n_in; (void)out_size; (void)ws_size;
  const float* mv    = (const float*)d_in[0];
  const float* ref   = (const float*)d_in[1];
  const float* s     = (const float*)d_in[2];
  // d_in[3..5] = basis/gp/jn tables: baked at compile time.
  const float* wlmv  = (const float*)d_in[6];
  const float* wls   = (const float*)d_in[7];
  const float* wrmv  = (const float*)d_in[8];
  const float* wrs   = (const float*)d_in[9];
  const float* wjlmv = (const float*)d_in[10];
  const float* wjls  = (const float*)d_in[11];
  const float* wjrmv = (const float*)d_in[12];
  const float* wjrs  = (const float*)d_in[13];
  const float* womv  = (const float*)d_in[14];
  const float* ws2mv = (const float*)d_in[15];
  const float* wm2s  = (const float*)d_in[16];
  const float* ws2s  = (const float*)d_in[17];

  float* out_mv = (float*)d_out;
  float* out_s  = out_mv + (size_t)NPOS_TOTAL * 32 * 16;
  uint4* wpk = (uint4*)d_ws;

  gb_prep<<<20, 256, 0, stream>>>(wlmv, wrmv, wjlmv, wjrmv, wls, wrs, wjls, wjrs,
                                  womv, ws2mv, wm2s, ws2s, wpk);
  gb_main<<<NPOS_TOTAL / 16, 256, 0, stream>>>(mv, ref, s, wpk, out_mv, out_s);
}